// Round 1
// baseline (611.853 us; speedup 1.0000x reference)
//
#include <hip/hip_runtime.h>

// Problem constants
#define B_ 2
#define S_ 5
#define C_ 256
#define H_ 192
#define W_ 192
#define K_ 7
#define NH_ 28
#define NW_ 28
#define HID_ 16

// g layout: [b][n][m][s][c]  -> ((b*NH+n)*NW+m)*(S_*C_) + s*C_ + c
// wt layout: [b][s][n][m]    -> ((b*S_+s)*NH+n)*NW + m

// Kernel 1: per-window means. One block per (b,s,c,n); 192 threads.
// Each thread sums its column over the 7 rows of the window band (clipped at
// H), then 28 threads reduce groups of 7 columns into window sums / 49.
__global__ void k_means(const float* __restrict__ x, float* __restrict__ g) {
    int idx = blockIdx.x;
    int n = idx % NH_; idx /= NH_;
    int c = idx % C_;  idx /= C_;
    int s = idx % S_;  idx /= S_;
    int b = idx;
    const float* plane = x + ((size_t)((b * S_ + s) * C_ + c)) * (H_ * W_);
    __shared__ float colsum[W_];
    int j = threadIdx.x;
    float acc = 0.f;
    int r0 = n * K_;
#pragma unroll
    for (int kh = 0; kh < K_; ++kh) {
        int r = r0 + kh;
        if (r < H_) acc += plane[r * W_ + j];   // uniform branch per block
    }
    colsum[j] = acc;
    __syncthreads();
    if (j < NW_) {
        float ssum = 0.f;
        int c0 = j * K_;
#pragma unroll
        for (int d = 0; d < K_; ++d) {
            int cc = c0 + d;
            if (cc < W_) ssum += colsum[cc];    // pad cols contribute 0
        }
        g[((size_t)((b * NH_ + n) * NW_ + j)) * (S_ * C_) + s * C_ + c] =
            ssum * (1.0f / 49.0f);
    }
}

// Kernel 2: tiny MLP over C + softmax over S. One block per (b,n,m) site,
// 5 waves (one per slice). Butterfly wave-reduction for the 256-dot products.
__global__ void k_mlp(const float* __restrict__ g, const float* __restrict__ w1,
                      const float* __restrict__ b1, const float* __restrict__ w2,
                      const float* __restrict__ b2, const float* __restrict__ sl,
                      float* __restrict__ wt) {
    int site = blockIdx.x;             // [0, B*NH*NW)
    int m = site % NW_;
    int n = (site / NW_) % NH_;
    int b = site / (NW_ * NH_);
    int s = threadIdx.x >> 6;          // wave index = slice
    int lane = threadIdx.x & 63;
    const float* gv = g + (size_t)site * (S_ * C_) + s * C_;
    float x0 = gv[lane];
    float x1 = gv[lane + 64];
    float x2 = gv[lane + 128];
    float x3 = gv[lane + 192];
    float logit = 0.f;
#pragma unroll
    for (int jj = 0; jj < HID_; ++jj) {
        const float* wr = w1 + jj * C_;
        float p = wr[lane] * x0 + wr[lane + 64] * x1 +
                  wr[lane + 128] * x2 + wr[lane + 192] * x3;
#pragma unroll
        for (int o = 1; o < 64; o <<= 1) p += __shfl_xor(p, o, 64);
        float h = p + b1[jj];
        h = h > 0.f ? h : 0.f;
        logit = fmaf(w2[jj], h, logit);
    }
    __shared__ float lg[S_];
    if (lane == 0) lg[s] = logit + b2[0] + sl[s];
    __syncthreads();
    if (threadIdx.x < S_) {
        int ss = threadIdx.x;
        float mx = lg[0];
#pragma unroll
        for (int t = 1; t < S_; ++t) mx = fmaxf(mx, lg[t]);
        float den = 0.f;
#pragma unroll
        for (int t = 0; t < S_; ++t) den += expf(lg[t] - mx);
        wt[((b * S_ + ss) * NH_ + n) * NW_ + m] = expf(lg[ss] - mx) / den;
    }
}

// Kernel 3: weighted gather into interleaved output layout.
// One block per (b,c,i) output row; 192 threads. Stage the 5 source rows in
// LDS (coalesced), read permuted (stride-7, conflict-free mod 32 banks),
// write the output row coalesced.
__global__ void k_out(const float* __restrict__ x, const float* __restrict__ wt,
                      float* __restrict__ out) {
    int idx = blockIdx.x;
    int i = idx % H_; idx /= H_;
    int c = idx % C_; idx /= C_;
    int b = idx;
    int n = i % NH_, kh = i / NH_;
    int r = n * K_ + kh;               // source row, may be in pad region
    int j = threadIdx.x;
    size_t obase = (((size_t)(b * C_ + c)) * H_ + i) * (size_t)W_;
    if (r >= H_) {                     // pad row -> whole output row is 0
        out[obase + j] = 0.f;
        return;
    }
    __shared__ float srow[S_][W_];
    __shared__ float wrow[S_][NW_];
#pragma unroll
    for (int s = 0; s < S_; ++s) {
        srow[s][j] = x[(((size_t)((b * S_ + s) * C_ + c)) * H_ + r) * W_ + j];
    }
    if (j < S_ * NW_) {
        int s = j / NW_, mm = j % NW_;
        wrow[s][mm] = wt[((b * S_ + s) * NH_ + n) * NW_ + mm];
    }
    __syncthreads();
    int m = j % NW_, kw = j / NW_;
    int col = m * K_ + kw;             // source col, may be in pad region
    float val = 0.f;
#pragma unroll
    for (int s = 0; s < S_; ++s) {
        float v = (col < W_) ? srow[s][col] : 0.f;
        val = fmaf(wrow[s][m], v, val);
    }
    out[obase + j] = val;
}

extern "C" void kernel_launch(void* const* d_in, const int* in_sizes, int n_in,
                              void* d_out, int out_size, void* d_ws, size_t ws_size,
                              hipStream_t stream) {
    const float* x  = (const float*)d_in[0];
    const float* w1 = (const float*)d_in[1];
    const float* b1 = (const float*)d_in[2];
    const float* w2 = (const float*)d_in[3];
    const float* b2 = (const float*)d_in[4];
    const float* sl = (const float*)d_in[5];
    float* out = (float*)d_out;

    float* g  = (float*)d_ws;                               // B*NH*NW*S*C floats = ~8 MB
    float* wt = g + (size_t)B_ * NH_ * NW_ * S_ * C_;       // B*S*NH*NW floats

    k_means<<<B_ * S_ * C_ * NH_, 192, 0, stream>>>(x, g);
    k_mlp<<<B_ * NH_ * NW_, 5 * 64, 0, stream>>>(g, w1, b1, w2, b2, sl, wt);
    k_out<<<B_ * C_ * H_, 192, 0, stream>>>(x, wt, out);
}